// Round 11
// baseline (214.012 us; speedup 1.0000x reference)
//
#include <hip/hip_runtime.h>
#include <hip/hip_fp16.h>

// ---------------- problem constants (match reference) ----------------
#define ES 256
#define NFEAT 42
#define NENT (8192 * 12)   // 98304 entities

// feature indices
#define F_SPECIES 0
#define F_ABILITY 1
#define F_ITEM 2
#define F_ITEM_EFFECT 3
#define F_GENDER 4
#define F_STATUS 5
#define F_BCB 6
#define F_TRAPPED 7
#define F_NEWSW 8
#define F_TOXIC 9
#define F_SLEEP 10
#define F_FAINTED 11
#define F_ACTIVE 12
#define F_SIDE 13
#define F_LEVEL 14
#define F_HP 15
#define F_MAXHP 16
#define F_BOOST0 17   // 7 boosts: 17..23
#define F_VOL0 24     // 9 vols: 24..32 (only first 7 matter after [:105] truncation)
#define F_MOVEID0 33  // 4 move ids
#define F_MOVEPP0 37  // 4 move pp

// ---------------- workspace layout (UNITS: halves) — all tables fp16 ----------------
#define OFF_HP     0                        // 1024 rows (hp-token bitsum + (v/1023)*OH0)
#define OFF_LV     (OFF_HP + 1024*ES)       //  128 rows
#define OFF_PP     (OFF_LV + 128*ES)        //   64 rows (row0 = 0)
#define OFF_VP     (OFF_PP + 64*ES)         //  784 rows (vol pairs t=0,1,2 + v6 single)
#define OFF_CA     (OFF_VP + 784*ES)        //  768 rows
#define OFF_CB     (OFF_CA + 768*ES)        // 1024 rows (+ all biases)
#define OFF_EI     (OFF_CB + 1024*ES)       //  500 rows (embed_item @ item_W[:256])
#define OFF_EM     (OFF_EI + 500*ES)        //  920 rows (embed_moves @ moves_W[:256])
#define OFF_SP     (OFF_EM + 920*ES)        // 1026 rows (fp16 embed_species)
#define OFF_AB     (OFF_SP + 1026*ES)       //  300 rows (fp16 embed_ability)
#define OFF_B01    (OFF_AB + 300*ES)        //  169 rows: (b0/2)W0+(b1/2)W1, idx (b0+6)*13+(b1+6)
#define OFF_B23    (OFF_B01 + 169*ES)       //  169 rows
#define OFF_B45    (OFF_B23 + 169*ES)       //  169 rows
#define OFF_B6     (OFF_B45 + 169*ES)       //   13 rows: (b6/2)W6
#define WS_HALVES  (OFF_B6 + 13*ES)         // ~3.6 MB (fits per-XCD L2)

// ---------------- helpers ----------------
typedef float vf4 __attribute__((ext_vector_type(4)));

__device__ __forceinline__ float4 ld4(const float* p) {
    return *reinterpret_cast<const float4*>(p);
}
__device__ __forceinline__ void st4_nt(float* p, const float4 v) {
    vf4 t = {v.x, v.y, v.z, v.w};
    __builtin_nontemporal_store(t, reinterpret_cast<vf4*>(p));
}
__device__ __forceinline__ void add4(float4& a, const float4 b) {
    a.x += b.x; a.y += b.y; a.z += b.z; a.w += b.w;
}
__device__ __forceinline__ float4 sum4(const float4 a, const float4 b) {
    return make_float4(a.x + b.x, a.y + b.y, a.z + b.z, a.w + b.w);
}
__device__ __forceinline__ void fma4(float4& a, float s, const float4 b) {
    a.x += s * b.x; a.y += s * b.y; a.z += s * b.z; a.w += s * b.w;
}
__device__ __forceinline__ int sclamp(int x, int lo, int hi) {
    return x < lo ? lo : (x > hi ? hi : x);
}
// store 4 floats as 4 halves (8B)
__device__ __forceinline__ void st4h(__half* p, const float4 v) {
    __half2 a = __floats2half2_rn(v.x, v.y);
    __half2 b = __floats2half2_rn(v.z, v.w);
    uint2 u;
    u.x = *reinterpret_cast<unsigned*>(&a);
    u.y = *reinterpret_cast<unsigned*>(&b);
    *reinterpret_cast<uint2*>(p) = u;
}

// ---------------- fused precompute kernel (4 rows/block, fp16 out) ----------------
#define TB_HP0 0        //  256 blocks
#define TB_LV0 256      //   32 blocks
#define TB_PP0 288      //   16 blocks
#define TB_VP0 304      //  196 blocks
#define TB_CA0 500      //  192 blocks
#define TB_CB0 692      //  256 blocks
#define TB_EI0 948      //  125 blocks
#define TB_EM0 1073     //  230 blocks
#define TB_SP0 1303     //  257 blocks (1026 rows, guarded)
#define TB_AB0 1560     //   75 blocks
#define TB_BP0 1635     //  130 blocks (520 boost-table rows)
#define TB_TOT 1765

__global__ __launch_bounds__(256) void k_tables(
    const float* __restrict__ sp_e, const float* __restrict__ ab_e,
    const float* __restrict__ item_e, const float* __restrict__ moves_e,
    const float* __restrict__ hp_W, const float* __restrict__ level_W,
    const float* __restrict__ moves_W, const float* __restrict__ vol_W,
    const float* __restrict__ item_W, const float* __restrict__ onehot_W,
    const float* __restrict__ active_W, const float* __restrict__ side_W,
    const float* __restrict__ boosts_W,
    const float* __restrict__ hp_b, const float* __restrict__ level_b,
    const float* __restrict__ active_b, const float* __restrict__ onehot_b,
    const float* __restrict__ boosts_b, const float* __restrict__ vol_b,
    const float* __restrict__ item_b, const float* __restrict__ side_b,
    const float* __restrict__ moves_b,
    __half* __restrict__ wh) {
    __shared__ float4 se4[4][64];
    const int bid = blockIdx.x, tid = threadIdx.x;
    const int rl = tid >> 6, lane = tid & 63, d0 = lane * 4;
    float4 acc = make_float4(0.f, 0.f, 0.f, 0.f);

    if (bid < TB_LV0) {                       // ---- Hp (+ folded (v/1023)*OH0)
        int v = (bid - TB_HP0) * 4 + rl;
        for (int b = 0; b < 10; ++b)
            if ((v >> b) & 1) add4(acc, ld4(hp_W + b * ES + d0));
        fma4(acc, (float)v * (1.0f / 1023.0f), ld4(onehot_W + d0));
        st4h(wh + OFF_HP + v * ES + d0, acc);
    } else if (bid < TB_PP0) {                // ---- Lv
        int v = (bid - TB_LV0) * 4 + rl;
        for (int b = 0; b < 7; ++b)
            if ((v >> b) & 1) add4(acc, ld4(level_W + b * ES + d0));
        st4h(wh + OFF_LV + v * ES + d0, acc);
    } else if (bid < TB_VP0) {                // ---- Pp
        int v = (bid - TB_PP0) * 4 + rl;
        for (int b = 0; b < 6; ++b)
            if ((v >> b) & 1) add4(acc, ld4(moves_W + (256 + b) * ES + d0));
        st4h(wh + OFF_PP + v * ES + d0, acc);
    } else if (bid < TB_CA0) {                // ---- VP nibble pairs + v6 single
        int v = (bid - TB_VP0) * 4 + rl;
        if (v < 768) {
            int t = v >> 8, pair = v & 255, a = pair >> 4, b = pair & 15;
            for (int j = 0; j < 16; ++j) {
                if (a & j) add4(acc, ld4(vol_W + (32 * t + j) * ES + d0));
                if (b & j) add4(acc, ld4(vol_W + (32 * t + 16 + j) * ES + d0));
            }
        } else {
            int a = v - 768;
            for (int j = 0; j < 9; ++j)       // rows 96..104 (< 105 truncation)
                if (a & j) add4(acc, ld4(vol_W + (96 + j) * ES + d0));
        }
        st4h(wh + OFF_VP + v * ES + d0, acc);
    } else if (bid < TB_CB0) {                // ---- combA
        int idx = (bid - TB_CA0) * 4 + rl;
        int fa = idx & 1, ns = (idx >> 1) & 1, tr = (idx >> 2) & 1, bcb = (idx >> 3) & 1;
        int rest = idx >> 4, g = rest % 3, e = rest / 3;
        acc = sum4(sum4(ld4(item_W + (256 + e) * ES + d0), ld4(onehot_W + (1 + g) * ES + d0)),
                   sum4(ld4(onehot_W + (12 + bcb) * ES + d0), ld4(onehot_W + (14 + tr) * ES + d0)));
        add4(acc, sum4(ld4(onehot_W + (16 + ns) * ES + d0), ld4(onehot_W + (30 + fa) * ES + d0)));
        st4h(wh + OFF_CA + idx * ES + d0, acc);
    } else if (bid < TB_EI0) {                // ---- combB (+ all biases)
        int idx = (bid - TB_CB0) * 4 + rl;
        int sd = idx & 1, act = (idx >> 1) & 1, sl = (idx >> 2) & 3,
            tox = (idx >> 4) & 7, st = idx >> 7;
        acc = sum4(sum4(ld4(hp_b + d0), ld4(level_b + d0)),
                   sum4(ld4(active_b + d0), ld4(onehot_b + d0)));
        add4(acc, sum4(ld4(boosts_b + d0), ld4(vol_b + d0)));
        add4(acc, sum4(ld4(item_b + d0), ld4(side_b + d0)));
        fma4(acc, 4.0f, ld4(moves_b + d0));
        add4(acc, sum4(ld4(onehot_W + (4 + st) * ES + d0), ld4(onehot_W + (18 + tox) * ES + d0)));
        add4(acc, sum4(ld4(onehot_W + (26 + sl) * ES + d0),
                       sum4(ld4(active_W + act * ES + d0), ld4(side_W + sd * ES + d0))));
        st4h(wh + OFF_CB + idx * ES + d0, acc);
    } else if (bid < TB_SP0) {                // ---- embmm: Eitem / Emoves
        const float* E; const float* W; __half* o; int r0;
        if (bid < TB_EM0) { E = item_e;  W = item_W;  o = wh + OFF_EI; r0 = (bid - TB_EI0) * 4; }
        else              { E = moves_e; W = moves_W; o = wh + OFF_EM; r0 = (bid - TB_EM0) * 4; }
        se4[tid >> 6][tid & 63] = ld4(E + r0 * ES + tid * 4);   // 4 rows staged
        __syncthreads();
#pragma unroll 4
        for (int k0 = 0; k0 < 64; ++k0) {
            float4 e4 = se4[rl][k0];
            fma4(acc, e4.x, ld4(W + (4 * k0 + 0) * ES + d0));
            fma4(acc, e4.y, ld4(W + (4 * k0 + 1) * ES + d0));
            fma4(acc, e4.z, ld4(W + (4 * k0 + 2) * ES + d0));
            fma4(acc, e4.w, ld4(W + (4 * k0 + 3) * ES + d0));
        }
        st4h(o + (r0 + rl) * ES + d0, acc);
    } else if (bid < TB_AB0) {                // ---- fp16 copy of embed_species
        int r = (bid - TB_SP0) * 4 + rl;
        if (r < 1026) st4h(wh + OFF_SP + r * ES + d0, ld4(sp_e + r * ES + d0));
    } else if (bid < TB_BP0) {                // ---- fp16 copy of embed_ability
        int r = (bid - TB_AB0) * 4 + rl;
        st4h(wh + OFF_AB + r * ES + d0, ld4(ab_e + r * ES + d0));
    } else {                                  // ---- boost tables (pre-scaled)
        int r = (bid - TB_BP0) * 4 + rl;      // 0..519
        if (r < 507) {
            int pair = r / 169;               // 0:(b0,b1) 1:(b2,b3) 2:(b4,b5)
            int rr = r - pair * 169;
            int i = rr / 13, j = rr % 13;
            fma4(acc, 0.5f * (float)(i - 6), ld4(boosts_W + (2 * pair) * ES + d0));
            fma4(acc, 0.5f * (float)(j - 6), ld4(boosts_W + (2 * pair + 1) * ES + d0));
            st4h(wh + OFF_B01 + r * ES + d0, acc);   // B01/B23/B45 contiguous
        } else {
            int b = r - 507;                  // 0..12
            fma4(acc, 0.5f * (float)(b - 6), ld4(boosts_W + 6 * ES + d0));
            st4h(wh + OFF_B6 + b * ES + d0, acc);
        }
    }
}

// ---------------- main gather kernel: TWO entities per wave, no LDS ----------------
// Lanes 0-31 = entity A, lanes 32-63 = entity B; each lane owns 8 dims (16B fp16).
// Per-wave VMEM: 2 feature loads + 23 gathers + 4 stores for 2 entities.

__global__ __launch_bounds__(256) void k_main(
    const int* __restrict__ ent,
    const __half* __restrict__ wh,
    float* __restrict__ out) {
    const int lane  = threadIdx.x & 63;
    const int wpair = __builtin_amdgcn_readfirstlane((blockIdx.x * 256 + threadIdx.x) >> 6);
    const int entA  = wpair * 2;            // this wave: entities entA, entA+1
    const int e     = lane >> 5;            // 0 = entity A half, 1 = entity B half
    const int sub   = lane & 31;
    const int sub16 = sub * 16;             // byte offset of this lane's 8 halves
    const int base  = entA * NFEAT;

    // feature vectors: flat ints [0..83] over the two entities
    const int fv  = __builtin_nontemporal_load(ent + base + lane);        // flats 0..63
    const int fv2 = __builtin_nontemporal_load(ent + base + 52 + sub);    // flats 52..83

#define RLA(i) __builtin_amdgcn_readlane(fv, (i))
#define RLB(i) ((i) < 22 ? __builtin_amdgcn_readlane(fv, 42 + (i)) \
                         : __builtin_amdgcn_readlane(fv2, (i) - 10))

    // ---- per-entity scalar BYTE offsets (SALU; row = idx*512 B) ----
#define GOFF(OFF, idx) (((OFF) * 2) + ((idx) << 9))
#define IDX_BLOCK(RL, S) \
    const int oCB##S = GOFF(OFF_CB, ((((RL(F_STATUS) & 7) * 8 + (RL(F_TOXIC) & 7)) * 4 + (RL(F_SLEEP) & 3)) * 2 + \
                        (RL(F_ACTIVE) & 1)) * 2 + (RL(F_SIDE) & 1)); \
    const int oCA##S = GOFF(OFF_CA, (((((RL(F_ITEM_EFFECT) & 15) * 3 + sclamp(RL(F_GENDER), 0, 2)) * 2 + \
                          (RL(F_BCB) & 1)) * 2 + (RL(F_TRAPPED) & 1)) * 2 + \
                        (RL(F_NEWSW) & 1)) * 2 + (RL(F_FAINTED) & 1)); \
    const int oSP##S = GOFF(OFF_SP, sclamp(RL(F_SPECIES), 0, 1025)); \
    const int oAB##S = GOFF(OFF_AB, sclamp(RL(F_ABILITY), 0, 299)); \
    const int oIT##S = GOFF(OFF_EI, sclamp(RL(F_ITEM), 0, 499)); \
    float hpv##S = (float)RL(F_HP); \
    int mh##S = RL(F_MAXHP); if (mh##S < 1) mh##S = 1; \
    const float ratio##S = fminf(fmaxf(hpv##S / (float)mh##S, 0.f), 1.f); \
    const int oHP##S = GOFF(OFF_HP, (int)floorf(1023.f * ratio##S)); \
    const int oLV##S = GOFF(OFF_LV, RL(F_LEVEL) & 127); \
    const int oV0##S = GOFF(OFF_VP, (0 * 256) + (((RL(F_VOL0 + 0) & 15) << 4) | (RL(F_VOL0 + 1) & 15))); \
    const int oV1##S = GOFF(OFF_VP, (1 * 256) + (((RL(F_VOL0 + 2) & 15) << 4) | (RL(F_VOL0 + 3) & 15))); \
    const int oV2##S = GOFF(OFF_VP, (2 * 256) + (((RL(F_VOL0 + 4) & 15) << 4) | (RL(F_VOL0 + 5) & 15))); \
    const int oV6##S = GOFF(OFF_VP, 768 + (RL(F_VOL0 + 6) & 15)); \
    const int oP0##S = GOFF(OFF_PP, RL(F_MOVEPP0 + 0) & 63); \
    const int oP1##S = GOFF(OFF_PP, RL(F_MOVEPP0 + 1) & 63); \
    const int oP2##S = GOFF(OFF_PP, RL(F_MOVEPP0 + 2) & 63); \
    const int oP3##S = GOFF(OFF_PP, RL(F_MOVEPP0 + 3) & 63); \
    const int oE0##S = GOFF(OFF_EM, sclamp(RL(F_MOVEID0 + 0), 0, 919)); \
    const int oE1##S = GOFF(OFF_EM, sclamp(RL(F_MOVEID0 + 1), 0, 919)); \
    const int oE2##S = GOFF(OFF_EM, sclamp(RL(F_MOVEID0 + 2), 0, 919)); \
    const int oE3##S = GOFF(OFF_EM, sclamp(RL(F_MOVEID0 + 3), 0, 919)); \
    const int oB0##S = GOFF(OFF_B01, (sclamp(RL(F_BOOST0 + 0), -6, 6) + 6) * 13 + (sclamp(RL(F_BOOST0 + 1), -6, 6) + 6)); \
    const int oB2##S = GOFF(OFF_B23, (sclamp(RL(F_BOOST0 + 2), -6, 6) + 6) * 13 + (sclamp(RL(F_BOOST0 + 3), -6, 6) + 6)); \
    const int oB4##S = GOFF(OFF_B45, (sclamp(RL(F_BOOST0 + 4), -6, 6) + 6) * 13 + (sclamp(RL(F_BOOST0 + 5), -6, 6) + 6)); \
    const int oB6##S = GOFF(OFF_B6, sclamp(RL(F_BOOST0 + 6), -6, 6) + 6);

    IDX_BLOCK(RLA, A)
    IDX_BLOCK(RLB, B)
#undef RLA
#undef RLB
#undef IDX_BLOCK
#undef GOFF

    const char* whb = reinterpret_cast<const char*>(wh);

    // ---- 23 gathers (dwordx4 = 8 halves/lane; half-wave per entity) ----
#define LD8(n, oX) const uint4 n = *reinterpret_cast<const uint4*>(whb + ((e ? oX##B : oX##A) + sub16))
    LD8(uCB, oCB);
    LD8(uCA, oCA);
    LD8(uSP, oSP);
    LD8(uAB, oAB);
    LD8(uIT, oIT);
    LD8(uHP, oHP);
    LD8(uLV, oLV);
    LD8(uV0, oV0);
    LD8(uV1, oV1);
    LD8(uV2, oV2);
    LD8(uV6, oV6);
    LD8(uP0, oP0);
    LD8(uP1, oP1);
    LD8(uP2, oP2);
    LD8(uP3, oP3);
    LD8(uE0, oE0);
    LD8(uE1, oE1);
    LD8(uE2, oE2);
    LD8(uE3, oE3);
    LD8(uB0, oB0);
    LD8(uB2, oB2);
    LD8(uB4, oB4);
    LD8(uB6, oB6);
#undef LD8

    float4 a0 = make_float4(0.f, 0.f, 0.f, 0.f);
    float4 a1 = make_float4(0.f, 0.f, 0.f, 0.f);
    // elementwise fadd(fpext(f16), f32) -> v_fma_mix_f32 (compiler mad-mix combine)
#define ACC(u) { \
    const __half* h = reinterpret_cast<const __half*>(&u); \
    a0.x += __half2float(h[0]); a0.y += __half2float(h[1]); \
    a0.z += __half2float(h[2]); a0.w += __half2float(h[3]); \
    a1.x += __half2float(h[4]); a1.y += __half2float(h[5]); \
    a1.z += __half2float(h[6]); a1.w += __half2float(h[7]); }
    ACC(uCB) ACC(uCA) ACC(uSP) ACC(uAB) ACC(uIT) ACC(uHP) ACC(uLV)
    ACC(uV0) ACC(uV1) ACC(uV2) ACC(uV6)
    ACC(uP0) ACC(uP1) ACC(uP2) ACC(uP3)
    ACC(uE0) ACC(uE1) ACC(uE2) ACC(uE3)
    ACC(uB0) ACC(uB2) ACC(uB4) ACC(uB6)
#undef ACC

    // ---- store: each half-wave writes its entity's contiguous 1 KB ----
    float* op = out + (entA + e) * ES + sub * 8;
    st4_nt(op, a0);
    st4_nt(op + 4, a1);
}

// ---------------- host launch ----------------

extern "C" void kernel_launch(void* const* d_in, const int* in_sizes, int n_in,
                              void* d_out, int out_size, void* d_ws, size_t ws_size,
                              hipStream_t stream) {
    const int*   entities = (const int*)  d_in[0];
    const float* sp       = (const float*)d_in[1];
    const float* ab       = (const float*)d_in[2];
    const float* item_e   = (const float*)d_in[3];
    const float* moves_e  = (const float*)d_in[4];
    const float* hp_W     = (const float*)d_in[5];
    const float* hp_b     = (const float*)d_in[6];
    const float* level_W  = (const float*)d_in[7];
    const float* level_b  = (const float*)d_in[8];
    const float* active_W = (const float*)d_in[9];
    const float* active_b = (const float*)d_in[10];
    const float* onehot_W = (const float*)d_in[11];
    const float* onehot_b = (const float*)d_in[12];
    const float* boosts_W = (const float*)d_in[13];
    const float* boosts_b = (const float*)d_in[14];
    const float* vol_W    = (const float*)d_in[15];
    const float* vol_b    = (const float*)d_in[16];
    const float* item_W   = (const float*)d_in[17];
    const float* item_b   = (const float*)d_in[18];
    const float* side_W   = (const float*)d_in[19];
    const float* side_b   = (const float*)d_in[20];
    const float* moves_W  = (const float*)d_in[21];
    const float* moves_b  = (const float*)d_in[22];

    __half* wh  = (__half*)d_ws;
    float*  out = (float*)d_out;

    k_tables<<<TB_TOT, 256, 0, stream>>>(
        sp, ab, item_e, moves_e, hp_W, level_W, moves_W, vol_W,
        item_W, onehot_W, active_W, side_W, boosts_W,
        hp_b, level_b, active_b, onehot_b, boosts_b,
        vol_b, item_b, side_b, moves_b, wh);

    // 2 entities per wave, 4 waves per block -> 8 entities/block
    k_main<<<NENT / 8, 256, 0, stream>>>(entities, wh, out);
}

// Round 14
// 211.977 us; speedup vs baseline: 1.0096x; 1.0096x over previous
//
#include <hip/hip_runtime.h>
#include <hip/hip_fp16.h>

// ---------------- problem constants (match reference) ----------------
#define ES 256
#define NFEAT 42
#define NENT (8192 * 12)   // 98304 entities

// feature indices
#define F_SPECIES 0
#define F_ABILITY 1
#define F_ITEM 2
#define F_ITEM_EFFECT 3
#define F_GENDER 4
#define F_STATUS 5
#define F_BCB 6
#define F_TRAPPED 7
#define F_NEWSW 8
#define F_TOXIC 9
#define F_SLEEP 10
#define F_FAINTED 11
#define F_ACTIVE 12
#define F_SIDE 13
#define F_LEVEL 14
#define F_HP 15
#define F_MAXHP 16
#define F_BOOST0 17   // 7 boosts: 17..23
#define F_VOL0 24     // 9 vols: 24..32 (only first 7 matter after [:105] truncation)
#define F_MOVEID0 33  // 4 move ids
#define F_MOVEPP0 37  // 4 move pp

// ---------------- workspace layout (UNITS: halves) — all tables fp16 ----------------
#define OFF_HP     0                         // 1024 rows (hp bitsum + (v/1023)*OH0)
#define OFF_LVQ    (OFF_HP   + 1024*ES)      // 2048 rows: (level<<4)|vol6
#define OFF_VP     (OFF_LVQ  + 2048*ES)      //  768 rows: vol nibble pairs t=0,1,2
#define OFF_CA     (OFF_VP   + 768*ES)       //  768 rows
#define OFF_CB     (OFF_CA   + 768*ES)       // 1024 rows (+ all biases)
#define OFF_EI     (OFF_CB   + 1024*ES)      //  500 rows (embed_item @ item_W[:256])
#define OFF_EM     (OFF_EI   + 500*ES)       //  920 rows (embed_moves @ moves_W[:256])
#define OFF_SP     (OFF_EM   + 920*ES)       // 1026 rows (fp16 embed_species)
#define OFF_AB     (OFF_SP   + 1026*ES)      //  300 rows (fp16 embed_ability)
#define OFF_B01    (OFF_AB   + 300*ES)       //  169 rows: (b0/2)W0+(b1/2)W1
#define OFF_B23    (OFF_B01  + 169*ES)       //  169 rows
#define OFF_B456   (OFF_B23  + 169*ES)       // 2197 rows: boosts 4,5,6 merged
#define OFF_PPP    (OFF_B456 + 2197*ES)      // 4096 rows: Pp[a]+Pp[b], idx=(a<<6)|b
#define WS_HALVES  (OFF_PPP  + 4096*ES)      // 15009 rows ~ 7.7 MB

// ---------------- helpers ----------------
typedef float vf4 __attribute__((ext_vector_type(4)));
typedef int   vi2 __attribute__((ext_vector_type(2)));

__device__ __forceinline__ float4 ld4(const float* p) {
    return *reinterpret_cast<const float4*>(p);
}
__device__ __forceinline__ void st4_nt(float* p, const float4 v) {
    vf4 t = {v.x, v.y, v.z, v.w};
    __builtin_nontemporal_store(t, reinterpret_cast<vf4*>(p));
}
__device__ __forceinline__ void add4(float4& a, const float4 b) {
    a.x += b.x; a.y += b.y; a.z += b.z; a.w += b.w;
}
__device__ __forceinline__ float4 sum4(const float4 a, const float4 b) {
    return make_float4(a.x + b.x, a.y + b.y, a.z + b.z, a.w + b.w);
}
__device__ __forceinline__ void fma4(float4& a, float s, const float4 b) {
    a.x += s * b.x; a.y += s * b.y; a.z += s * b.z; a.w += s * b.w;
}
__device__ __forceinline__ int sclamp(int x, int lo, int hi) {
    return x < lo ? lo : (x > hi ? hi : x);
}
__device__ __forceinline__ void st4h(__half* p, const float4 v) {
    __half2 a = __floats2half2_rn(v.x, v.y);
    __half2 b = __floats2half2_rn(v.z, v.w);
    uint2 u;
    u.x = *reinterpret_cast<unsigned*>(&a);
    u.y = *reinterpret_cast<unsigned*>(&b);
    *reinterpret_cast<uint2*>(p) = u;
}

// ---------------- fused precompute kernel (4 rows/block, fp16 out) ----------------
#define TB_HP0    0      //  256 blocks
#define TB_LVQ0   256    //  512 blocks (2048 rows)
#define TB_VP0    768    //  192 blocks (768 rows)
#define TB_CA0    960    //  192 blocks
#define TB_CB0    1152   //  256 blocks
#define TB_EI0    1408   //  125 blocks
#define TB_EM0    1533   //  230 blocks
#define TB_SP0    1763   //  257 blocks (1026 rows, guarded)
#define TB_AB0    2020   //   75 blocks
#define TB_B01_0  2095   //   43 blocks (169 rows, guarded)
#define TB_B23_0  2138   //   43 blocks (169 rows, guarded)
#define TB_B456_0 2181   //  550 blocks (2197 rows, guarded)
#define TB_PPP0   2731   // 1024 blocks (4096 rows)
#define TB_TOT    3755

__global__ __launch_bounds__(256) void k_tables(
    const float* __restrict__ sp_e, const float* __restrict__ ab_e,
    const float* __restrict__ item_e, const float* __restrict__ moves_e,
    const float* __restrict__ hp_W, const float* __restrict__ level_W,
    const float* __restrict__ moves_W, const float* __restrict__ vol_W,
    const float* __restrict__ item_W, const float* __restrict__ onehot_W,
    const float* __restrict__ active_W, const float* __restrict__ side_W,
    const float* __restrict__ boosts_W,
    const float* __restrict__ hp_b, const float* __restrict__ level_b,
    const float* __restrict__ active_b, const float* __restrict__ onehot_b,
    const float* __restrict__ boosts_b, const float* __restrict__ vol_b,
    const float* __restrict__ item_b, const float* __restrict__ side_b,
    const float* __restrict__ moves_b,
    __half* __restrict__ wh) {
    __shared__ float4 se4[4][64];
    const int bid = blockIdx.x, tid = threadIdx.x;
    const int rl = tid >> 6, lane = tid & 63, d0 = lane * 4;
    float4 acc = make_float4(0.f, 0.f, 0.f, 0.f);

    if (bid < TB_LVQ0) {                      // ---- Hp (+ folded (v/1023)*OH0)
        int v = (bid - TB_HP0) * 4 + rl;
        for (int b = 0; b < 10; ++b)
            if ((v >> b) & 1) add4(acc, ld4(hp_W + b * ES + d0));
        fma4(acc, (float)v * (1.0f / 1023.0f), ld4(onehot_W + d0));
        st4h(wh + OFF_HP + v * ES + d0, acc);
    } else if (bid < TB_VP0) {                // ---- LVQ: (level<<4)|vol6
        int v = (bid - TB_LVQ0) * 4 + rl;
        int lv = v >> 4, c = v & 15;
        for (int b = 0; b < 7; ++b)
            if ((lv >> b) & 1) add4(acc, ld4(level_W + b * ES + d0));
        for (int j = 1; j < 9; ++j)           // rows 96..104 (< 105 truncation)
            if (c & j) add4(acc, ld4(vol_W + (96 + j) * ES + d0));
        st4h(wh + OFF_LVQ + v * ES + d0, acc);
    } else if (bid < TB_CA0) {                // ---- VP nibble pairs (t = 0,1,2)
        int v = (bid - TB_VP0) * 4 + rl;
        int t = v >> 8, pair = v & 255, a = pair >> 4, b = pair & 15;
        for (int j = 0; j < 16; ++j) {
            if (a & j) add4(acc, ld4(vol_W + (32 * t + j) * ES + d0));
            if (b & j) add4(acc, ld4(vol_W + (32 * t + 16 + j) * ES + d0));
        }
        st4h(wh + OFF_VP + v * ES + d0, acc);
    } else if (bid < TB_CB0) {                // ---- combA
        int idx = (bid - TB_CA0) * 4 + rl;
        int fa = idx & 1, ns = (idx >> 1) & 1, tr = (idx >> 2) & 1, bcb = (idx >> 3) & 1;
        int rest = idx >> 4, g = rest % 3, e = rest / 3;
        acc = sum4(sum4(ld4(item_W + (256 + e) * ES + d0), ld4(onehot_W + (1 + g) * ES + d0)),
                   sum4(ld4(onehot_W + (12 + bcb) * ES + d0), ld4(onehot_W + (14 + tr) * ES + d0)));
        add4(acc, sum4(ld4(onehot_W + (16 + ns) * ES + d0), ld4(onehot_W + (30 + fa) * ES + d0)));
        st4h(wh + OFF_CA + idx * ES + d0, acc);
    } else if (bid < TB_EI0) {                // ---- combB (+ all biases)
        int idx = (bid - TB_CB0) * 4 + rl;
        int sd = idx & 1, act = (idx >> 1) & 1, sl = (idx >> 2) & 3,
            tox = (idx >> 4) & 7, st = idx >> 7;
        acc = sum4(sum4(ld4(hp_b + d0), ld4(level_b + d0)),
                   sum4(ld4(active_b + d0), ld4(onehot_b + d0)));
        add4(acc, sum4(ld4(boosts_b + d0), ld4(vol_b + d0)));
        add4(acc, sum4(ld4(item_b + d0), ld4(side_b + d0)));
        fma4(acc, 4.0f, ld4(moves_b + d0));
        add4(acc, sum4(ld4(onehot_W + (4 + st) * ES + d0), ld4(onehot_W + (18 + tox) * ES + d0)));
        add4(acc, sum4(ld4(onehot_W + (26 + sl) * ES + d0),
                       sum4(ld4(active_W + act * ES + d0), ld4(side_W + sd * ES + d0))));
        st4h(wh + OFF_CB + idx * ES + d0, acc);
    } else if (bid < TB_SP0) {                // ---- embmm: Eitem / Emoves
        const float* E; const float* W; __half* o; int r0;
        if (bid < TB_EM0) { E = item_e;  W = item_W;  o = wh + OFF_EI; r0 = (bid - TB_EI0) * 4; }
        else              { E = moves_e; W = moves_W; o = wh + OFF_EM; r0 = (bid - TB_EM0) * 4; }
        se4[tid >> 6][tid & 63] = ld4(E + r0 * ES + tid * 4);   // 4 rows staged
        __syncthreads();
#pragma unroll 4
        for (int k0 = 0; k0 < 64; ++k0) {
            float4 e4 = se4[rl][k0];
            fma4(acc, e4.x, ld4(W + (4 * k0 + 0) * ES + d0));
            fma4(acc, e4.y, ld4(W + (4 * k0 + 1) * ES + d0));
            fma4(acc, e4.z, ld4(W + (4 * k0 + 2) * ES + d0));
            fma4(acc, e4.w, ld4(W + (4 * k0 + 3) * ES + d0));
        }
        st4h(o + (r0 + rl) * ES + d0, acc);
    } else if (bid < TB_AB0) {                // ---- fp16 copy of embed_species
        int r = (bid - TB_SP0) * 4 + rl;
        if (r < 1026) st4h(wh + OFF_SP + r * ES + d0, ld4(sp_e + r * ES + d0));
    } else if (bid < TB_B01_0) {              // ---- fp16 copy of embed_ability
        int r = (bid - TB_AB0) * 4 + rl;
        st4h(wh + OFF_AB + r * ES + d0, ld4(ab_e + r * ES + d0));
    } else if (bid < TB_B23_0) {              // ---- B01
        int r = (bid - TB_B01_0) * 4 + rl;
        if (r < 169) {
            int i = r / 13, j = r % 13;
            fma4(acc, 0.5f * (float)(i - 6), ld4(boosts_W + 0 * ES + d0));
            fma4(acc, 0.5f * (float)(j - 6), ld4(boosts_W + 1 * ES + d0));
            st4h(wh + OFF_B01 + r * ES + d0, acc);
        }
    } else if (bid < TB_B456_0) {             // ---- B23
        int r = (bid - TB_B23_0) * 4 + rl;
        if (r < 169) {
            int i = r / 13, j = r % 13;
            fma4(acc, 0.5f * (float)(i - 6), ld4(boosts_W + 2 * ES + d0));
            fma4(acc, 0.5f * (float)(j - 6), ld4(boosts_W + 3 * ES + d0));
            st4h(wh + OFF_B23 + r * ES + d0, acc);
        }
    } else if (bid < TB_PPP0) {               // ---- B456 (boosts 4,5,6)
        int r = (bid - TB_B456_0) * 4 + rl;
        if (r < 2197) {
            int i = r / 169, rem = r % 169, j = rem / 13, k = rem % 13;
            fma4(acc, 0.5f * (float)(i - 6), ld4(boosts_W + 4 * ES + d0));
            fma4(acc, 0.5f * (float)(j - 6), ld4(boosts_W + 5 * ES + d0));
            fma4(acc, 0.5f * (float)(k - 6), ld4(boosts_W + 6 * ES + d0));
            st4h(wh + OFF_B456 + r * ES + d0, acc);
        }
    } else {                                  // ---- PPP: pp pairs, coeff in {0,1,2}
        int v = (bid - TB_PPP0) * 4 + rl;
        int a = v >> 6, b = v & 63;
        for (int j = 0; j < 6; ++j) {
            float c = (float)(((a >> j) & 1) + ((b >> j) & 1));
            fma4(acc, c, ld4(moves_W + (256 + j) * ES + d0));
        }
        st4h(wh + OFF_PPP + v * ES + d0, acc);
    }
}

// ---------------- main gather kernel: TWO entities per wave ----------------
// Lanes 0-31 = entity A, lanes 32-63 = entity B; each lane owns 8 dims (16B fp16).
// Per-wave VMEM: 1 feature load + 19 gathers + 2 stores = 22 for 2 entities.

__global__ __launch_bounds__(256) void k_main(
    const int* __restrict__ ent,
    const __half* __restrict__ wh,
    float* __restrict__ out) {
    const int lane  = threadIdx.x & 63;
    const int wpair = __builtin_amdgcn_readfirstlane((blockIdx.x * 256 + threadIdx.x) >> 6);
    const int entA  = wpair * 2;
    const int e     = lane >> 5;            // 0 = entity A half, 1 = entity B half
    const int sub   = lane & 31;
    const int sub16 = sub * 16;             // byte offset of this lane's 8 halves
    const int base  = entA * NFEAT;

    // ONE dwordx2 load covers both entities' 84 ints (lanes 0..41 hold flats 0..83).
    const int li = lane < 42 ? lane : 41;   // clamp: avoids OOB on the final wave
    const vi2 fp = __builtin_nontemporal_load(reinterpret_cast<const vi2*>(ent + base) + li);
    const int fpx = fp.x, fpy = fp.y;

#define RLF(f) __builtin_amdgcn_readlane(((f) & 1) ? fpy : fpx, (f) >> 1)
#define RLA(i) RLF(i)
#define RLB(i) RLF(42 + (i))

    // ---- per-entity scalar BYTE offsets (row = idx*512 B) ----
#define GOFF(OFF, idx) (((OFF) * 2) + ((idx) << 9))
#define IDX_BLOCK(RL, S) \
    const int oCB##S = GOFF(OFF_CB, ((((RL(F_STATUS) & 7) * 8 + (RL(F_TOXIC) & 7)) * 4 + (RL(F_SLEEP) & 3)) * 2 + \
                        (RL(F_ACTIVE) & 1)) * 2 + (RL(F_SIDE) & 1)); \
    const int oCA##S = GOFF(OFF_CA, (((((RL(F_ITEM_EFFECT) & 15) * 3 + sclamp(RL(F_GENDER), 0, 2)) * 2 + \
                          (RL(F_BCB) & 1)) * 2 + (RL(F_TRAPPED) & 1)) * 2 + \
                        (RL(F_NEWSW) & 1)) * 2 + (RL(F_FAINTED) & 1)); \
    const int oSP##S = GOFF(OFF_SP, sclamp(RL(F_SPECIES), 0, 1025)); \
    const int oAB##S = GOFF(OFF_AB, sclamp(RL(F_ABILITY), 0, 299)); \
    const int oIT##S = GOFF(OFF_EI, sclamp(RL(F_ITEM), 0, 499)); \
    float hpv##S = (float)RL(F_HP); \
    int mh##S = RL(F_MAXHP); if (mh##S < 1) mh##S = 1; \
    const float ratio##S = fminf(fmaxf(hpv##S / (float)mh##S, 0.f), 1.f); \
    const int oHP##S = GOFF(OFF_HP, (int)floorf(1023.f * ratio##S)); \
    const int oLQ##S = GOFF(OFF_LVQ, ((RL(F_LEVEL) & 127) << 4) | (RL(F_VOL0 + 6) & 15)); \
    const int oV0##S = GOFF(OFF_VP, (0 * 256) + (((RL(F_VOL0 + 0) & 15) << 4) | (RL(F_VOL0 + 1) & 15))); \
    const int oV1##S = GOFF(OFF_VP, (1 * 256) + (((RL(F_VOL0 + 2) & 15) << 4) | (RL(F_VOL0 + 3) & 15))); \
    const int oV2##S = GOFF(OFF_VP, (2 * 256) + (((RL(F_VOL0 + 4) & 15) << 4) | (RL(F_VOL0 + 5) & 15))); \
    const int oPa##S = GOFF(OFF_PPP, ((RL(F_MOVEPP0 + 0) & 63) << 6) | (RL(F_MOVEPP0 + 1) & 63)); \
    const int oPb##S = GOFF(OFF_PPP, ((RL(F_MOVEPP0 + 2) & 63) << 6) | (RL(F_MOVEPP0 + 3) & 63)); \
    const int oE0##S = GOFF(OFF_EM, sclamp(RL(F_MOVEID0 + 0), 0, 919)); \
    const int oE1##S = GOFF(OFF_EM, sclamp(RL(F_MOVEID0 + 1), 0, 919)); \
    const int oE2##S = GOFF(OFF_EM, sclamp(RL(F_MOVEID0 + 2), 0, 919)); \
    const int oE3##S = GOFF(OFF_EM, sclamp(RL(F_MOVEID0 + 3), 0, 919)); \
    const int oB0##S = GOFF(OFF_B01, (sclamp(RL(F_BOOST0 + 0), -6, 6) + 6) * 13 + (sclamp(RL(F_BOOST0 + 1), -6, 6) + 6)); \
    const int oB2##S = GOFF(OFF_B23, (sclamp(RL(F_BOOST0 + 2), -6, 6) + 6) * 13 + (sclamp(RL(F_BOOST0 + 3), -6, 6) + 6)); \
    const int oB4##S = GOFF(OFF_B456, ((sclamp(RL(F_BOOST0 + 4), -6, 6) + 6) * 13 + \
                          (sclamp(RL(F_BOOST0 + 5), -6, 6) + 6)) * 13 + (sclamp(RL(F_BOOST0 + 6), -6, 6) + 6));

    IDX_BLOCK(RLA, A)
    IDX_BLOCK(RLB, B)
#undef RLA
#undef RLB
#undef RLF
#undef IDX_BLOCK
#undef GOFF

    const char* whb = reinterpret_cast<const char*>(wh);

    // ---- 19 gathers (dwordx4 = 8 halves/lane; half-wave per entity) ----
#define LD8(n, oX) const uint4 n = *reinterpret_cast<const uint4*>(whb + ((e ? oX##B : oX##A) + sub16))
    LD8(uCB, oCB);
    LD8(uCA, oCA);
    LD8(uSP, oSP);
    LD8(uAB, oAB);
    LD8(uIT, oIT);
    LD8(uHP, oHP);
    LD8(uLQ, oLQ);
    LD8(uV0, oV0);
    LD8(uV1, oV1);
    LD8(uV2, oV2);
    LD8(uPa, oPa);
    LD8(uPb, oPb);
    LD8(uE0, oE0);
    LD8(uE1, oE1);
    LD8(uE2, oE2);
    LD8(uE3, oE3);
    LD8(uB0, oB0);
    LD8(uB2, oB2);
    LD8(uB4, oB4);
#undef LD8

    float4 a0 = make_float4(0.f, 0.f, 0.f, 0.f);
    float4 a1 = make_float4(0.f, 0.f, 0.f, 0.f);
#define ACC(u) { \
    const __half* h = reinterpret_cast<const __half*>(&u); \
    a0.x += __half2float(h[0]); a0.y += __half2float(h[1]); \
    a0.z += __half2float(h[2]); a0.w += __half2float(h[3]); \
    a1.x += __half2float(h[4]); a1.y += __half2float(h[5]); \
    a1.z += __half2float(h[6]); a1.w += __half2float(h[7]); }
    ACC(uCB) ACC(uCA) ACC(uSP) ACC(uAB) ACC(uIT) ACC(uHP) ACC(uLQ)
    ACC(uV0) ACC(uV1) ACC(uV2)
    ACC(uPa) ACC(uPb)
    ACC(uE0) ACC(uE1) ACC(uE2) ACC(uE3)
    ACC(uB0) ACC(uB2) ACC(uB4)
#undef ACC

    // ---- store: each half-wave writes its entity's contiguous 1 KB ----
    float* op = out + (entA + e) * ES + sub * 8;
    st4_nt(op, a0);
    st4_nt(op + 4, a1);
}

// ---------------- host launch ----------------

extern "C" void kernel_launch(void* const* d_in, const int* in_sizes, int n_in,
                              void* d_out, int out_size, void* d_ws, size_t ws_size,
                              hipStream_t stream) {
    const int*   entities = (const int*)  d_in[0];
    const float* sp       = (const float*)d_in[1];
    const float* ab       = (const float*)d_in[2];
    const float* item_e   = (const float*)d_in[3];
    const float* moves_e  = (const float*)d_in[4];
    const float* hp_W     = (const float*)d_in[5];
    const float* hp_b     = (const float*)d_in[6];
    const float* level_W  = (const float*)d_in[7];
    const float* level_b  = (const float*)d_in[8];
    const float* active_W = (const float*)d_in[9];
    const float* active_b = (const float*)d_in[10];
    const float* onehot_W = (const float*)d_in[11];
    const float* onehot_b = (const float*)d_in[12];
    const float* boosts_W = (const float*)d_in[13];
    const float* boosts_b = (const float*)d_in[14];
    const float* vol_W    = (const float*)d_in[15];
    const float* vol_b    = (const float*)d_in[16];
    const float* item_W   = (const float*)d_in[17];
    const float* item_b   = (const float*)d_in[18];
    const float* side_W   = (const float*)d_in[19];
    const float* side_b   = (const float*)d_in[20];
    const float* moves_W  = (const float*)d_in[21];
    const float* moves_b  = (const float*)d_in[22];

    __half* wh  = (__half*)d_ws;
    float*  out = (float*)d_out;

    k_tables<<<TB_TOT, 256, 0, stream>>>(
        sp, ab, item_e, moves_e, hp_W, level_W, moves_W, vol_W,
        item_W, onehot_W, active_W, side_W, boosts_W,
        hp_b, level_b, active_b, onehot_b, boosts_b,
        vol_b, item_b, side_b, moves_b, wh);

    // 2 entities per wave, 4 waves per block -> 8 entities/block
    k_main<<<NENT / 8, 256, 0, stream>>>(entities, wh, out);
}